// Round 6
// baseline (570.264 us; speedup 1.0000x reference)
//
#include <hip/hip_runtime.h>
#include <math.h>

#define CCH 64
#define NSP 64
#define TAU 0.25f   // |pivot|^2 threshold for the fast pivot path

// ---------------------------------------------------------------------------
// Kernel 1: circular 3x3 conv, per-sample kernels, + bias, + identity kernel.
// (round-1 version; revisit after logdet stops dominating)
// ---------------------------------------------------------------------------
__global__ __launch_bounds__(256) void conv_kernel(
    const float* __restrict__ x, const float* __restrict__ K,
    const float* __restrict__ bias, float* __restrict__ out) {
  int bid = blockIdx.x;            // 0..255
  int b = bid >> 6, co = bid & 63;
  __shared__ float w[CCH * 9];
  __shared__ float tile[64 * 65];
  int t = threadIdx.x;

  for (int i = t; i < CCH * 9; i += 256) {
    float v = K[(size_t)((b * 64 + co) * 64) * 9 + i];
    if (i == co * 9 + 4) v += 1.0f;   // identity: ci==co, kh=kw=1
    w[i] = v;
  }

  int ty = t >> 2;
  int tx = t & 3;
  int x0 = tx << 4;
  float bval = bias[b * 64 + co];
  float acc[16];
#pragma unroll
  for (int i = 0; i < 16; ++i) acc[i] = bval;

  const float* xb = x + (size_t)(b * 64) * 4096;
  for (int ci = 0; ci < 64; ++ci) {
    __syncthreads();
    const float* xc = xb + (size_t)ci * 4096;
#pragma unroll
    for (int j = 0; j < 16; ++j) {
      int i = t + 256 * j;
      tile[(i >> 6) * 65 + (i & 63)] = xc[i];
    }
    __syncthreads();

    float w0 = w[ci * 9 + 0], w1 = w[ci * 9 + 1], w2 = w[ci * 9 + 2];
    float w3 = w[ci * 9 + 3], w4 = w[ci * 9 + 4], w5 = w[ci * 9 + 5];
    float w6 = w[ci * 9 + 6], w7 = w[ci * 9 + 7], w8 = w[ci * 9 + 8];

    int ym = ((ty - 1) & 63) * 65;
    int yc = ty * 65;
    int yp = ((ty + 1) & 63) * 65;
    float in0[18], in1[18], in2[18];
#pragma unroll
    for (int ix = 0; ix < 18; ++ix) {
      int xx = (x0 + ix - 1) & 63;
      in0[ix] = tile[ym + xx];
      in1[ix] = tile[yc + xx];
      in2[ix] = tile[yp + xx];
    }
#pragma unroll
    for (int px = 0; px < 16; ++px) {
      float a = acc[px];
      a = fmaf(w0, in0[px], a); a = fmaf(w1, in0[px + 1], a); a = fmaf(w2, in0[px + 2], a);
      a = fmaf(w3, in1[px], a); a = fmaf(w4, in1[px + 1], a); a = fmaf(w5, in1[px + 2], a);
      a = fmaf(w6, in2[px], a); a = fmaf(w7, in2[px + 1], a); a = fmaf(w8, in2[px + 2], a);
      acc[px] = a;
    }
  }

  float* op = out + (size_t)(b * 64 + co) * 4096 + ty * 64 + x0;
#pragma unroll
  for (int i = 0; i < 16; i += 4) {
    *(float4*)(op + i) = make_float4(acc[i], acc[i + 1], acc[i + 2], acc[i + 3]);
  }
}

// ---------------------------------------------------------------------------
// Kernel 2: per-frequency 64x64 complex LU -> sum log|pivot|.
// TWO waves per matrix: lane r of wave w owns row r, global columns c with
// (c & 1) == w, column-compacted per wave (32 complex + pad = 66 floats/lane,
// fully VGPR-resident under the 256-reg budget -> no AGPR moves, no spill).
// Global front column k has parity k&1, so the front wave alternates and load
// stays balanced. Per step: front wave picks the pivot (threshold ballot),
// computes per-row multipliers, publishes (f_r, p) via parity-double-buffered
// LDS; ONE barrier; each wave updates its own columns, readlane-ing the pivot
// row's entries from its own lane p. Retired/pivot rows run with f=0.
// Double-buffer safety: the step-k read of buffer (k&1) and its step-(k+2)
// rewrite are separated by the step-(k+1) barrier.
// ---------------------------------------------------------------------------
__device__ __forceinline__ float rlane(float x, int lane) {
  return __int_as_float(__builtin_amdgcn_readlane(__float_as_int(x), lane));
}

__global__ __launch_bounds__(128, 2) void logdet_kernel(
    const float* __restrict__ K, float* __restrict__ logdet) {
  int key = blockIdx.x;                      // 0..4095
  int u = key >> 6, v = key & 63;
  int key2 = (((64 - u) & 63) << 6) | ((64 - v) & 63);
  if (key2 < key) return;                    // conjugate partner, weight 2 below
  float weight = (key2 == key) ? 1.0f : 2.0f;
  int b = blockIdx.y;

  int t = threadIdx.x;
  int wv = t >> 6;                           // wave id: owns columns c&1==wv
  int r = t & 63;                            // lane == matrix row

  __shared__ float2 fbuf[2][64];             // multipliers, double-buffered by parity
  __shared__ int pbuf[2];                    // pivot lane, double-buffered

  // twiddles w[kh*3+kw] = e^{-2*pi*i*(u*kh+v*kw)/64} via complex power products
  float Ar[3], Ai[3], Br[3], Bi[3];
  {
    const float k2pi = -6.283185307179586f / 64.0f;
    float su, cu, sv, cv;
    __sincosf(k2pi * (float)u, &su, &cu);
    __sincosf(k2pi * (float)v, &sv, &cv);
    Ar[0] = 1.0f; Ai[0] = 0.0f; Ar[1] = cu; Ai[1] = su;
    Ar[2] = cu * cu - su * su; Ai[2] = 2.0f * cu * su;
    Br[0] = 1.0f; Bi[0] = 0.0f; Br[1] = cv; Bi[1] = sv;
    Br[2] = cv * cv - sv * sv; Bi[2] = 2.0f * cv * sv;
  }
  float wr[9], wi[9];
#pragma unroll
  for (int kh = 0; kh < 3; ++kh)
#pragma unroll
    for (int kw = 0; kw < 3; ++kw) {
      wr[kh * 3 + kw] = Ar[kh] * Br[kw] - Ai[kh] * Bi[kw];
      wi[kh * 3 + kw] = Ar[kh] * Bi[kw] + Ai[kh] * Br[kw];
    }

  // Build my 32 columns of Khat row r: local slot j <-> global column 2j+wv.
  float ar[33], ai[33];
  const float* Kp = K + (size_t)(b * 64 + r) * 576;
#pragma unroll
  for (int j = 0; j < 32; ++j) {
    int c = 2 * j + wv;
    const float* kc = Kp + c * 9;
    float re = 0.0f, im = 0.0f;
#pragma unroll
    for (int t9 = 0; t9 < 9; ++t9) {
      float kv = kc[t9];
      re = fmaf(kv, wr[t9], re);
      im = fmaf(kv, wi[t9], im);
    }
    if (c == r) { re += wr[4]; im += wi[4]; }  // identity: center-tap delta
    ar[j] = re; ai[j] = im;
  }
  ar[32] = 0.0f; ai[32] = 0.0f;              // pad for chunk-rounded guards

  bool active = true;
  float logsum = 0.0f;

  for (int k = 0; k < 63; ++k) {
    int fw = k & 1;                          // front wave == buffer parity
    bool amFront = (wv == fw);               // wave-uniform branch
    int p = 0;
    float fre = 0.0f, fim = 0.0f;

    if (amFront) {
      float mag = fmaf(ar[0], ar[0], ai[0] * ai[0]);
      bool cand = active && (mag >= TAU);
      unsigned long long cm = __ballot(cand);
      if (cm != 0ULL) {
        p = __ffsll(cm) - 1;                 // fast path: first big-enough pivot
      } else {                               // rare: all remaining pivots tiny
        float mm = active ? mag : -1.0f;
#pragma unroll
        for (int off = 32; off > 0; off >>= 1) mm = fmaxf(mm, __shfl_xor(mm, off));
        unsigned long long mx = __ballot(active && (mag == mm));
        if (mx == 0ULL) mx = __ballot(active);   // degenerate (NaN) guard
        p = __ffsll(mx) - 1;
      }
      p = __builtin_amdgcn_readfirstlane(p) & 63;  // uniform, always valid lane
      float pr = rlane(ar[0], p);
      float pi = rlane(ai[0], p);
      float inv = 1.0f / fmaf(pr, pr, pi * pi);
      fre = (ar[0] * pr + ai[0] * pi) * inv;
      fim = (ai[0] * pr - ar[0] * pi) * inv;
      bool use = active && (r != p);
      fre = use ? fre : 0.0f;                // pivot + retired rows: no-op update
      fim = use ? fim : 0.0f;
      if (r == p) { logsum += 0.5f * __logf(mag); active = false; }
      fbuf[fw][r] = make_float2(fre, fim);
      if (r == 0) pbuf[fw] = p;
    }
    __syncthreads();                         // one barrier per step

    if (amFront) {
      // shift-update my slots 1..remF-1 down to 0..remF-2
      int remF = 32 - (k >> 1);              // my remaining columns at entry
#pragma unroll
      for (int ch = 0; ch < 4; ++ch) {
        if (ch * 8 < remF - 1) {             // uniform scalar guard
#pragma unroll
          for (int e = 0; e < 8; ++e) {
            int c = ch * 8 + e + 1;          // 1..32 (slot 32 = pad)
            float lr = rlane(ar[c], p);      // pivot row entry, own wave's lane p
            float li = rlane(ai[c], p);
            ar[c - 1] = fmaf(fim, li, fmaf(-fre, lr, ar[c]));
            ai[c - 1] = fmaf(-fim, lr, fmaf(-fre, li, ai[c]));
          }
        }
      }
    } else {
      p = __builtin_amdgcn_readfirstlane(pbuf[fw]) & 63;
      float2 f2 = fbuf[fw][r];
      fre = f2.x; fim = f2.y;
      if (r == p) active = false;            // track retirement for future fronting
      int remO = 32 - ((k + 1) >> 1);        // my columns, updated in place
#pragma unroll
      for (int ch = 0; ch < 4; ++ch) {
        if (ch * 8 < remO) {                 // uniform scalar guard
#pragma unroll
          for (int e = 0; e < 8; ++e) {
            int c = ch * 8 + e;              // 0..31 (remO<=32, pad never hit)
            float lr = rlane(ar[c], p);
            float li = rlane(ai[c], p);
            ar[c] = fmaf(fim, li, fmaf(-fre, lr, ar[c]));
            ai[c] = fmaf(-fim, lr, fmaf(-fre, li, ai[c]));
          }
        }
      }
    }
  }

  // final pivot: global column 63 (parity 1) = wave 1, slot 0; exactly one
  // row still active in each wave's tracking.
  if (wv == 1 && active) {
    logsum += 0.5f * __logf(fmaf(ar[0], ar[0], ai[0] * ai[0]));
  }

#pragma unroll
  for (int off = 32; off > 0; off >>= 1) logsum += __shfl_xor(logsum, off);
  if (r == 0) atomicAdd(&logdet[b], weight * logsum);
}

// ---------------------------------------------------------------------------
extern "C" void kernel_launch(void* const* d_in, const int* in_sizes, int n_in,
                              void* d_out, int out_size, void* d_ws, size_t ws_size,
                              hipStream_t stream) {
  const float* conv_in = (const float*)d_in[0];   // [4,64,64,64]
  const float* K       = (const float*)d_in[1];   // [4,64,64,3,3]
  const float* bias    = (const float*)d_in[2];   // [4,64,1,1]
  float* out = (float*)d_out;                     // conv_out (1048576) ++ logdet (4)
  float* logdet = out + 1048576;

  hipMemsetAsync(logdet, 0, 4 * sizeof(float), stream);
  conv_kernel<<<dim3(256), dim3(256), 0, stream>>>(conv_in, K, bias, out);
  logdet_kernel<<<dim3(4096, 4), dim3(128), 0, stream>>>(K, logdet);
}

// Round 7
// 504.454 us; speedup vs baseline: 1.1305x; 1.1305x over previous
//
#include <hip/hip_runtime.h>
#include <math.h>

#define CCH 64
#define NSP 64
#define TAU 0.25f   // |pivot|^2 threshold for the fast pivot path

// ---------------------------------------------------------------------------
// Kernel 1: circular 3x3 conv, per-sample kernels, + bias, + identity kernel.
// (round-1 version; revisit once logdet stops dominating)
// ---------------------------------------------------------------------------
__global__ __launch_bounds__(256) void conv_kernel(
    const float* __restrict__ x, const float* __restrict__ K,
    const float* __restrict__ bias, float* __restrict__ out) {
  int bid = blockIdx.x;            // 0..255
  int b = bid >> 6, co = bid & 63;
  __shared__ float w[CCH * 9];
  __shared__ float tile[64 * 65];
  int t = threadIdx.x;

  for (int i = t; i < CCH * 9; i += 256) {
    float v = K[(size_t)((b * 64 + co) * 64) * 9 + i];
    if (i == co * 9 + 4) v += 1.0f;   // identity: ci==co, kh=kw=1
    w[i] = v;
  }

  int ty = t >> 2;
  int tx = t & 3;
  int x0 = tx << 4;
  float bval = bias[b * 64 + co];
  float acc[16];
#pragma unroll
  for (int i = 0; i < 16; ++i) acc[i] = bval;

  const float* xb = x + (size_t)(b * 64) * 4096;
  for (int ci = 0; ci < 64; ++ci) {
    __syncthreads();
    const float* xc = xb + (size_t)ci * 4096;
#pragma unroll
    for (int j = 0; j < 16; ++j) {
      int i = t + 256 * j;
      tile[(i >> 6) * 65 + (i & 63)] = xc[i];
    }
    __syncthreads();

    float w0 = w[ci * 9 + 0], w1 = w[ci * 9 + 1], w2 = w[ci * 9 + 2];
    float w3 = w[ci * 9 + 3], w4 = w[ci * 9 + 4], w5 = w[ci * 9 + 5];
    float w6 = w[ci * 9 + 6], w7 = w[ci * 9 + 7], w8 = w[ci * 9 + 8];

    int ym = ((ty - 1) & 63) * 65;
    int yc = ty * 65;
    int yp = ((ty + 1) & 63) * 65;
    float in0[18], in1[18], in2[18];
#pragma unroll
    for (int ix = 0; ix < 18; ++ix) {
      int xx = (x0 + ix - 1) & 63;
      in0[ix] = tile[ym + xx];
      in1[ix] = tile[yc + xx];
      in2[ix] = tile[yp + xx];
    }
#pragma unroll
    for (int px = 0; px < 16; ++px) {
      float a = acc[px];
      a = fmaf(w0, in0[px], a); a = fmaf(w1, in0[px + 1], a); a = fmaf(w2, in0[px + 2], a);
      a = fmaf(w3, in1[px], a); a = fmaf(w4, in1[px + 1], a); a = fmaf(w5, in1[px + 2], a);
      a = fmaf(w6, in2[px], a); a = fmaf(w7, in2[px + 1], a); a = fmaf(w8, in2[px + 2], a);
      acc[px] = a;
    }
  }

  float* op = out + (size_t)(b * 64 + co) * 4096 + ty * 64 + x0;
#pragma unroll
  for (int i = 0; i < 16; i += 4) {
    *(float4*)(op + i) = make_float4(acc[i], acc[i + 1], acc[i + 2], acc[i + 3]);
  }
}

// ---------------------------------------------------------------------------
// Kernel 2: per-frequency 64x64 complex LU -> sum log|pivot|.
// One wave per canonical (b,u,v); lane r owns row r, column-compacted so the
// pivot column is always register index 0. Pivot row broadcast via
// v_readlane (uniform lane index) -- no LDS, no barriers anywhere.
// DELTA vs round 4: __launch_bounds__(64, 1) -> 512-reg budget so the RA has
// no occupancy incentive to park ar[]/ai[] in AGPRs (gfx950 unified file
// makes that parking pure overhead: accvgpr_read/write on every access).
// HW still fits 2 waves/SIMD at <=256 regs, same occupancy as round 4.
// ---------------------------------------------------------------------------
__device__ __forceinline__ float rlane(float x, int lane) {
  return __int_as_float(__builtin_amdgcn_readlane(__float_as_int(x), lane));
}

__global__ __launch_bounds__(64, 1) void logdet_kernel(
    const float* __restrict__ K, float* __restrict__ logdet) {
  int u = blockIdx.x >> 6, v = blockIdx.x & 63;
  int b = blockIdx.y;
  int key = blockIdx.x;
  int key2 = (((64 - u) & 63) << 6) | ((64 - v) & 63);
  if (key2 < key) return;                    // conjugate partner, weight 2 below
  float weight = (key2 == key) ? 1.0f : 2.0f;

  int r = threadIdx.x;                       // lane == matrix row

  // twiddles w[kh*3+kw] = e^{-2*pi*i*(u*kh+v*kw)/64} via complex power products
  float Ar[3], Ai[3], Br[3], Bi[3];
  {
    const float k2pi = -6.283185307179586f / 64.0f;
    float su, cu, sv, cv;
    __sincosf(k2pi * (float)u, &su, &cu);
    __sincosf(k2pi * (float)v, &sv, &cv);
    Ar[0] = 1.0f; Ai[0] = 0.0f; Ar[1] = cu; Ai[1] = su;
    Ar[2] = cu * cu - su * su; Ai[2] = 2.0f * cu * su;
    Br[0] = 1.0f; Bi[0] = 0.0f; Br[1] = cv; Bi[1] = sv;
    Br[2] = cv * cv - sv * sv; Bi[2] = 2.0f * cv * sv;
  }
  float wr[9], wi[9];
#pragma unroll
  for (int kh = 0; kh < 3; ++kh)
#pragma unroll
    for (int kw = 0; kw < 3; ++kw) {
      wr[kh * 3 + kw] = Ar[kh] * Br[kw] - Ai[kh] * Bi[kw];
      wi[kh * 3 + kw] = Ar[kh] * Bi[kw] + Ai[kh] * Br[kw];
    }

  // Build row r of Khat with aligned float4 loads (row = 576 floats)
  float ar[65], ai[65];
  const float4* Kp4 = (const float4*)(K + (size_t)(b * 64 + r) * 576);
#pragma unroll
  for (int g = 0; g < 16; ++g) {             // 16 groups x 4 columns
    float f[36];
#pragma unroll
    for (int qq = 0; qq < 9; ++qq) {
      float4 vv = Kp4[g * 9 + qq];
      f[qq * 4 + 0] = vv.x; f[qq * 4 + 1] = vv.y; f[qq * 4 + 2] = vv.z; f[qq * 4 + 3] = vv.w;
    }
#pragma unroll
    for (int cc = 0; cc < 4; ++cc) {
      int c = g * 4 + cc;
      float re = 0.0f, im = 0.0f;
#pragma unroll
      for (int t9 = 0; t9 < 9; ++t9) {
        float kv = f[cc * 9 + t9];
        re = fmaf(kv, wr[t9], re);
        im = fmaf(kv, wi[t9], im);
      }
      if (c == r) { re += wr[4]; im += wi[4]; }  // identity: center-tap delta
      ar[c] = re; ai[c] = im;
    }
  }
  ar[64] = 0.0f; ai[64] = 0.0f;              // pad slot read by chunk 3

  bool active = true;
  float logsum = 0.0f;

  for (int k = 0; k < 63; ++k) {
    float mag = fmaf(ar[0], ar[0], ai[0] * ai[0]);
    bool cand = active && (mag >= TAU);
    unsigned long long candm = __ballot(cand);
    int p;
    if (candm != 0ULL) {
      p = __ffsll(candm) - 1;                // fast path: first big-enough pivot
    } else {                                 // rare: all remaining pivots tiny
      float mm = active ? mag : -1.0f;
#pragma unroll
      for (int off = 32; off > 0; off >>= 1) mm = fmaxf(mm, __shfl_xor(mm, off));
      unsigned long long mx = __ballot(active && (mag == mm));
      if (mx == 0ULL) mx = __ballot(active); // degenerate (NaN) guard
      p = __ffsll(mx) - 1;
    }
    p = __builtin_amdgcn_readfirstlane(p) & 63;  // uniform, always-valid lane

    if (r == p) {                            // retire pivot lane: log its pivot
      logsum += 0.5f * __logf(mag);
      active = false;
    }

    float pr = rlane(ar[0], p);
    float pi = rlane(ai[0], p);
    float inv = 1.0f / fmaf(pr, pr, pi * pi);
    float fre = (ar[0] * pr + ai[0] * pi) * inv;
    float fim = (ai[0] * pr - ar[0] * pi) * inv;
    fre = active ? fre : 0.0f;               // pivot + retired lanes: shift-only
    fim = active ? fim : 0.0f;

    int rem = 63 - k;                        // remaining columns at indices 1..rem
#pragma unroll
    for (int ch = 0; ch < 4; ++ch) {
      if (ch * 16 < rem) {                   // uniform scalar guard
#pragma unroll
        for (int j = 0; j < 16; ++j) {
          int c = ch * 16 + j + 1;
          float lr = rlane(ar[c], p);        // lane p's ar[c] not yet overwritten
          float li = rlane(ai[c], p);
          float nr = fmaf(fim, li, fmaf(-fre, lr, ar[c]));
          float ni = fmaf(-fim, lr, fmaf(-fre, li, ai[c]));
          ar[c - 1] = nr;                    // compaction shift
          ai[c - 1] = ni;
        }
      }
    }
  }
  if (active) logsum += 0.5f * __logf(fmaf(ar[0], ar[0], ai[0] * ai[0]));

#pragma unroll
  for (int off = 32; off > 0; off >>= 1) logsum += __shfl_xor(logsum, off);
  if (r == 0) atomicAdd(&logdet[b], weight * logsum);
}

// ---------------------------------------------------------------------------
extern "C" void kernel_launch(void* const* d_in, const int* in_sizes, int n_in,
                              void* d_out, int out_size, void* d_ws, size_t ws_size,
                              hipStream_t stream) {
  const float* conv_in = (const float*)d_in[0];   // [4,64,64,64]
  const float* K       = (const float*)d_in[1];   // [4,64,64,3,3]
  const float* bias    = (const float*)d_in[2];   // [4,64,1,1]
  float* out = (float*)d_out;                     // conv_out (1048576) ++ logdet (4)
  float* logdet = out + 1048576;

  hipMemsetAsync(logdet, 0, 4 * sizeof(float), stream);
  conv_kernel<<<dim3(256), dim3(256), 0, stream>>>(conv_in, K, bias, out);
  logdet_kernel<<<dim3(4096, 4), dim3(64), 0, stream>>>(K, logdet);
}